// Round 7
// baseline (7267.579 us; speedup 1.0000x reference)
//
#include <hip/hip_runtime.h>
#include <stdint.h>

#define E    512
#define H    8
#define DH   64
#define BB   8
#define SS   24
#define FF   2048
#define NL   3
#define VTOK 32000
#define LBUF 25
#define ML   24
#define START_ID 1

// ---------------------------------------------------------------------------
// Encoder embedding + sinusoidal PE (double to match numpy)
// ---------------------------------------------------------------------------
__global__ void enc_embed_kernel(const int* __restrict__ inp, const float* __restrict__ emb,
                                 float* __restrict__ x) {
  int r = blockIdx.x;
  int s = r / BB, b = r % BB;
  int tok = inp[b * SS + s];
  const float* er = emb + (size_t)tok * E;
  for (int e = threadIdx.x; e < E; e += blockDim.x) {
    int j = e >> 1;
    double dv = exp(-((double)(2 * j)) * (log(10000.0) / (double)E));
    double ang = (double)s * dv;
    double pe = (e & 1) ? cos(ang) : sin(ang);
    x[(size_t)r * E + e] = er[e] + (float)pe;
  }
}

// ---------------------------------------------------------------------------
// In-place per-row LayerNorm of the block's 8x512 LDS tile.
// ---------------------------------------------------------------------------
__device__ __forceinline__ void ln_tile(float* Al, const float* __restrict__ g,
                                        const float* __restrict__ b,
                                        float* rm, float* rrs) {
  int t = threadIdx.x;
  int rr = t >> 5, q = t & 31;
  const float* ar = Al + rr * 512;
  float sm = 0.f, s2 = 0.f;
  for (int j = q; j < 512; j += 32) { float v = ar[j]; sm += v; s2 += v * v; }
  for (int off = 16; off; off >>= 1) {
    sm += __shfl_down(sm, off, 32);
    s2 += __shfl_down(s2, off, 32);
  }
  if (q == 0) {
    float m = sm * (1.0f / 512.0f);
    float var = s2 * (1.0f / 512.0f) - m * m;
    rm[rr] = m;
    rrs[rr] = 1.0f / sqrtf(var + 1e-5f);
  }
  __syncthreads();
  for (int idx = t; idx < 4096; idx += 256) {
    int r2 = idx >> 9, c2 = idx & 511;
    Al[idx] = (Al[idx] - rm[r2]) * rrs[r2] * g[c2] + b[c2];
  }
  __syncthreads();
}

// ---------------------------------------------------------------------------
// Fast GEMM: C[M,N] = A[M,K] @ W[K,N(ldw)] (+bias,resid,relu / or partials)
// grid (N/64, S, M/8), block 256.
// A-source modes:
//   gtok  != null : A rows gathered from gemb via token ids (embed fusion)
//   rpart != null : A = rbias + rresid + sum_{s<rS} rpart[s]  (partial-reduce fusion)
//   else          : A loaded from A[M,K] at kbase
// lng  != null : per-row LN of the 8x512 A tile (requires K=512, kbase=0)
// lng2 != null : second stacked LN (encoder final: LN_l2 then LN_ng)
// astore       : blocks with (bx==0,by==0) write their post-LN tile to
//                astore + row0*512
// ---------------------------------------------------------------------------
__global__ __launch_bounds__(256) void fgemm_kernel(
    const float* __restrict__ A, int K,
    const float* __restrict__ W, int ldw, int N,
    const float* __restrict__ bias,
    const float* __restrict__ resid,
    float* __restrict__ C, int relu,
    unsigned long long* __restrict__ amax,
    const float* __restrict__ lng, const float* __restrict__ lnb,
    const float* __restrict__ lng2, const float* __restrict__ lnb2,
    float* __restrict__ astore,
    const int* __restrict__ gtok, const float* __restrict__ gemb,
    const float* __restrict__ rpart, const float* __restrict__ rbias,
    const float* __restrict__ rresid, int rS) {
  __shared__ float Al[8 * 512];      // 16 KB
  __shared__ float red[16 * 512];    // 32 KB
  __shared__ float rm[8], rrs[8];
  int t = threadIdx.x;
  int c0 = blockIdx.x * 64;
  int s = blockIdx.y;
  int row0 = blockIdx.z * 8;
  int kbase = s * 512;
  if (gtok) {
    for (int i = t; i < 1024; i += 256) {
      int r = i >> 7, cc = i & 127;
      int tok = gtok[r];
      ((float4*)Al)[i] = *(const float4*)(gemb + (size_t)tok * E + (cc << 2));
    }
  } else if (rpart) {
    for (int i = t; i < 1024; i += 256) {
      int r = i >> 7, cc = i & 127;
      int c = cc << 2;
      float4 v = *(const float4*)(rbias + c);
      float4 rv = *(const float4*)(rresid + (size_t)r * E + c);
      v.x += rv.x; v.y += rv.y; v.z += rv.z; v.w += rv.w;
      for (int sl = 0; sl < rS; ++sl) {
        float4 pv = *(const float4*)(rpart + ((size_t)sl * 8 + r) * E + c);
        v.x += pv.x; v.y += pv.y; v.z += pv.z; v.w += pv.w;
      }
      ((float4*)Al)[i] = v;
    }
  } else {
    for (int i = t; i < 1024; i += 256) {
      int r = i >> 7, cc = i & 127;
      ((float4*)Al)[i] = *(const float4*)(A + (size_t)(row0 + r) * K + kbase + (cc << 2));
    }
  }
  __syncthreads();
  if (lng) {
    ln_tile(Al, lng, lnb, rm, rrs);
    if (lng2) ln_tile(Al, lng2, lnb2, rm, rrs);
  }
  if (astore && blockIdx.x == 0 && blockIdx.y == 0) {
    float* ap = astore + (size_t)row0 * 512;
    for (int idx = t; idx < 4096; idx += 256) ap[idx] = Al[idx];
  }
  int tc = t & 15, tk = t >> 4;
  int col = c0 + (tc << 2);
  float acc[8][4];
#pragma unroll
  for (int m = 0; m < 8; ++m) { acc[m][0] = acc[m][1] = acc[m][2] = acc[m][3] = 0.f; }
  const float4* wp = (const float4*)(W + (size_t)kbase * ldw + col);
  const size_t ld4 = (size_t)(ldw >> 2);
#pragma unroll 16
  for (int i = 0; i < 32; ++i) {
    int k = tk + (i << 4);
    float4 wv = wp[(size_t)k * ld4];
#pragma unroll
    for (int m = 0; m < 8; ++m) {
      float a = Al[m * 512 + k];
      acc[m][0] += a * wv.x; acc[m][1] += a * wv.y;
      acc[m][2] += a * wv.z; acc[m][3] += a * wv.w;
    }
  }
#pragma unroll
  for (int m = 0; m < 8; ++m) {
    float4* rr2 = (float4*)&red[tk * 512 + m * 64 + (tc << 2)];
    *rr2 = make_float4(acc[m][0], acc[m][1], acc[m][2], acc[m][3]);
  }
  __syncthreads();
  float out2[2];
#pragma unroll
  for (int j = 0; j < 2; ++j) {
    int o = t + j * 256;
    float v = 0.f;
#pragma unroll
    for (int sl = 0; sl < 16; ++sl) v += red[sl * 512 + o];
    out2[j] = v;
  }
  int S = gridDim.y;
  if (S > 1) {
    int M = gridDim.z * 8;
#pragma unroll
    for (int j = 0; j < 2; ++j) {
      int o = t + j * 256; int m = o >> 6, cc = o & 63;
      C[((size_t)s * M + row0 + m) * N + c0 + cc] = out2[j];
    }
  } else {
#pragma unroll
    for (int j = 0; j < 2; ++j) {
      int o = t + j * 256; int m = o >> 6, cc = o & 63;
      int col2 = c0 + cc;
      float v = out2[j] + bias[col2];
      if (resid) v += resid[(size_t)(row0 + m) * N + col2];
      if (relu) v = fmaxf(v, 0.0f);
      C[(size_t)(row0 + m) * N + col2] = v;
      out2[j] = v;
    }
    if (amax) {
      __syncthreads();
      unsigned long long* keys = (unsigned long long*)red;
#pragma unroll
      for (int j = 0; j < 2; ++j) {
        int o = t + j * 256;
        unsigned int fb = __float_as_uint(out2[j]);
        fb = (fb & 0x80000000u) ? ~fb : (fb | 0x80000000u);
        int col2 = c0 + (o & 63);
        keys[o] = ((unsigned long long)fb << 32) |
                  (unsigned long long)(0xFFFFFFFFu - (unsigned)col2);
      }
      __syncthreads();
      if (t < 64) {
        for (int m = 0; m < 8; ++m) {
          unsigned long long k = keys[m * 64 + t];
          for (int off = 32; off; off >>= 1) {
            unsigned long long o2 = __shfl_down(k, off);
            if (o2 > k) k = o2;
          }
          if (t == 0) atomicMax(&amax[m], k);
        }
      }
    }
  }
}

// ---------------------------------------------------------------------------
// Reduce S partial slices + bias + resid (encoder FFN2). grid = M rows.
// ---------------------------------------------------------------------------
__global__ __launch_bounds__(256) void reduce_br_kernel(const float* __restrict__ part, int S, int M,
                                 const float* __restrict__ bias,
                                 const float* __restrict__ resid,
                                 float* __restrict__ outp) {
  int r = blockIdx.x, t = threadIdx.x;
#pragma unroll
  for (int j = 0; j < 2; ++j) {
    int c = t + j * 256;
    float v = bias[c] + resid[(size_t)r * E + c];
    for (int s = 0; s < S; ++s) v += part[((size_t)s * M + r) * E + c];
    outp[(size_t)r * E + c] = v;
  }
}

// ---------------------------------------------------------------------------
// Reduce S partial slices + bias + resid + LayerNorm (decoder FFN2). grid 8.
// ---------------------------------------------------------------------------
__global__ __launch_bounds__(256) void reduce_ln_kernel(const float* __restrict__ part, int S,
                                 const float* __restrict__ bias,
                                 const float* __restrict__ resid,
                                 const float* __restrict__ g, const float* __restrict__ bta,
                                 float* __restrict__ out) {
  int b = blockIdx.x, t = threadIdx.x;
  float v0 = bias[t] + resid[(size_t)b * E + t];
  float v1 = bias[t + 256] + resid[(size_t)b * E + t + 256];
  for (int s = 0; s < S; ++s) {
    v0 += part[((size_t)s * 8 + b) * E + t];
    v1 += part[((size_t)s * 8 + b) * E + t + 256];
  }
  __shared__ float red[256];
  red[t] = v0 + v1;
  __syncthreads();
  for (int s = 128; s > 0; s >>= 1) { if (t < s) red[t] += red[t + s]; __syncthreads(); }
  float m = red[0] * (1.0f / (float)E);
  __syncthreads();
  float d0 = v0 - m, d1 = v1 - m;
  red[t] = d0 * d0 + d1 * d1;
  __syncthreads();
  for (int s = 128; s > 0; s >>= 1) { if (t < s) red[t] += red[t + s]; __syncthreads(); }
  float v = red[0] * (1.0f / (float)E);
  float rstd = 1.0f / sqrtf(v + 1e-5f);
  out[(size_t)b * E + t]       = d0 * rstd * g[t]       + bta[t];
  out[(size_t)b * E + t + 256] = d1 * rstd * g[t + 256] + bta[t + 256];
}

// ---------------------------------------------------------------------------
// Encoder self-attention: block per (b,h), 256 threads.
// ---------------------------------------------------------------------------
__global__ void enc_attn_kernel(const float* __restrict__ qkv, float* __restrict__ o) {
  int b = blockIdx.x >> 3, h = blockIdx.x & 7;
  __shared__ float qs[SS * DH], ks[SS * DH], vs[SS * DH];
  __shared__ float sc[SS][SS];
  int t = threadIdx.x;
  for (int idx = t; idx < SS * DH; idx += 256) {
    int srow = idx / DH, d = idx - srow * DH;
    size_t base = ((size_t)(srow * BB + b)) * (3 * E) + h * DH + d;
    qs[idx] = qkv[base];
    ks[idx] = qkv[base + E];
    vs[idx] = qkv[base + 2 * E];
  }
  __syncthreads();
  for (int p = t; p < SS * SS; p += 256) {
    int qi = p / SS, kj = p - qi * SS;
    float a = 0.f;
    for (int d = 0; d < DH; ++d) a += qs[qi * DH + d] * ks[kj * DH + d];
    sc[qi][kj] = a * 0.125f;
  }
  __syncthreads();
  if (t < SS) {
    float mx = -1e30f;
    for (int j = 0; j < SS; ++j) mx = fmaxf(mx, sc[t][j]);
    float sm = 0.f;
    for (int j = 0; j < SS; ++j) { float ev = expf(sc[t][j] - mx); sc[t][j] = ev; sm += ev; }
    float inv = 1.0f / sm;
    for (int j = 0; j < SS; ++j) sc[t][j] *= inv;
  }
  __syncthreads();
  for (int p = t; p < SS * DH; p += 256) {
    int qi = p / DH, d = p - qi * DH;
    float a = 0.f;
    for (int j = 0; j < SS; ++j) a += sc[qi][j] * vs[j * DH + d];
    o[((size_t)(qi * BB + b)) * E + h * DH + d] = a;
  }
}

// ---------------------------------------------------------------------------
// Decoder self-attn + PARTIAL out-proj. grid 64=(b,h), 256 threads.
// Block (b,h): updates KV cache slice, computes attention output o[64],
// then its 64-row slab of the out-proj:  part[h][b][c] = o . W[h*64: ,c].
// Consumer reduces the 8 head-slices deterministically (rpart path, rS=8).
// ---------------------------------------------------------------------------
__global__ __launch_bounds__(256) void dec_sa_part_kernel(
    const float* __restrict__ qkv,   // [8][1536]
    float* __restrict__ Kc, float* __restrict__ Vc, int pos,
    const float* __restrict__ W,     // saow [512][512]
    float* __restrict__ part) {      // [8][8][512]
  int b = blockIdx.x >> 3, h = blockIdx.x & 7;
  int t = threadIdx.x;
  __shared__ float qs[DH], os[DH];
  __shared__ float sc[32];
  const float* base = qkv + (size_t)b * 1536 + h * DH;
  if (t < DH) {
    qs[t] = base[t];
    Kc[((size_t)pos * BB + b) * E + h * DH + t] = base[512 + t];
    Vc[((size_t)pos * BB + b) * E + h * DH + t] = base[1024 + t];
  }
  __syncthreads();
  int L = pos + 1;
  if (t < L) {
    const float4* k4 = (t == pos) ? (const float4*)(base + 512)
                                  : (const float4*)(Kc + ((size_t)t * BB + b) * E + h * DH);
    const float4* q4 = (const float4*)qs;
    float a = 0.f;
#pragma unroll
    for (int d = 0; d < 16; ++d) {
      float4 qv = q4[d], kv = k4[d];
      a += qv.x * kv.x + qv.y * kv.y + qv.z * kv.z + qv.w * kv.w;
    }
    sc[t] = a * 0.125f;
  }
  __syncthreads();
  if (t == 0) {
    float mx = -1e30f;
    for (int j = 0; j < L; ++j) mx = fmaxf(mx, sc[j]);
    float sm = 0.f;
    for (int j = 0; j < L; ++j) { float ev = expf(sc[j] - mx); sc[j] = ev; sm += ev; }
    float inv = 1.0f / sm;
    for (int j = 0; j < L; ++j) sc[j] *= inv;
  }
  __syncthreads();
  if (t < DH) {
    float a = 0.f;
    for (int j = 0; j < L; ++j) {
      float vv = (j == pos) ? base[1024 + t]
                            : Vc[((size_t)j * BB + b) * E + h * DH + t];
      a += sc[j] * vv;
    }
    os[t] = a;
  }
  __syncthreads();
  float p0 = 0.f, p1 = 0.f;
  const float* wr = W + (size_t)h * DH * E;   // 64 rows, ld 512
#pragma unroll 8
  for (int d = 0; d < DH; ++d) {
    float o = os[d];
    p0 += o * wr[(size_t)d * E + t];
    p1 += o * wr[(size_t)d * E + t + 256];
  }
  float* pp = part + ((size_t)h * BB + b) * E;
  pp[t] = p0; pp[t + 256] = p1;
}

// ---------------------------------------------------------------------------
// Decoder cross-attn + PARTIAL out-proj. grid 64=(b,h), 256 threads.
// ---------------------------------------------------------------------------
__global__ __launch_bounds__(256) void dec_ca_part_kernel(
    const float* __restrict__ q,     // qca [8][512]
    const float* __restrict__ Km, const float* __restrict__ Vm,  // [192][512]
    const float* __restrict__ W,     // caow [512][512]
    float* __restrict__ part) {      // [8][8][512]
  int b = blockIdx.x >> 3, h = blockIdx.x & 7;
  int t = threadIdx.x;
  __shared__ float qs[DH], os[DH];
  __shared__ float sc[SS];
  if (t < DH) qs[t] = q[(size_t)b * E + h * DH + t];
  __syncthreads();
  if (t < SS) {
    const float4* k4 = (const float4*)(Km + ((size_t)t * BB + b) * E + h * DH);
    const float4* q4 = (const float4*)qs;
    float a = 0.f;
#pragma unroll
    for (int d = 0; d < 16; ++d) {
      float4 qv = q4[d], kv = k4[d];
      a += qv.x * kv.x + qv.y * kv.y + qv.z * kv.z + qv.w * kv.w;
    }
    sc[t] = a * 0.125f;
  }
  __syncthreads();
  if (t == 0) {
    float mx = -1e30f;
    for (int j = 0; j < SS; ++j) mx = fmaxf(mx, sc[j]);
    float sm = 0.f;
    for (int j = 0; j < SS; ++j) { float ev = expf(sc[j] - mx); sc[j] = ev; sm += ev; }
    float inv = 1.0f / sm;
    for (int j = 0; j < SS; ++j) sc[j] *= inv;
  }
  __syncthreads();
  if (t < DH) {
    float a = 0.f;
    for (int j = 0; j < SS; ++j)
      a += sc[j] * Vm[((size_t)j * BB + b) * E + h * DH + t];
    os[t] = a;
  }
  __syncthreads();
  float p0 = 0.f, p1 = 0.f;
  const float* wr = W + (size_t)h * DH * E;
#pragma unroll 8
  for (int d = 0; d < DH; ++d) {
    float o = os[d];
    p0 += o * wr[(size_t)d * E + t];
    p1 += o * wr[(size_t)d * E + t + 256];
  }
  float* pp = part + ((size_t)h * BB + b) * E;
  pp[t] = p0; pp[t + 256] = p1;
}

// ---------------------------------------------------------------------------
__global__ void dec_init_kernel(int* __restrict__ tokens, unsigned long long* __restrict__ amax) {
  int t = threadIdx.x;
  if (t < BB) { tokens[t] = START_ID; amax[t] = 0ull; }
}

__global__ void next_token_kernel(unsigned long long* __restrict__ amax, int* __restrict__ tokens,
                                  float* __restrict__ outtok, int i) {
  int t = threadIdx.x;
  if (t < BB) {
    unsigned long long p = amax[t];
    int idx = (int)(0xFFFFFFFFu - (unsigned int)(p & 0xFFFFFFFFull));
    tokens[(i + 1) * BB + t] = idx;
    outtok[i * BB + t] = (float)idx;
    amax[t] = 0ull;
  }
}

// ---------------------------------------------------------------------------
extern "C" void kernel_launch(void* const* d_in, const int* in_sizes, int n_in,
                              void* d_out, int out_size, void* d_ws, size_t ws_size,
                              hipStream_t stream) {
  (void)in_sizes; (void)n_in; (void)out_size; (void)ws_size;
  const int*   inp   = (const int*)d_in[0];
  const float* emb   = (const float*)d_in[1];
  const float* e_aw  = (const float*)d_in[2];
  const float* e_ab  = (const float*)d_in[3];
  const float* e_aow = (const float*)d_in[4];
  const float* e_aob = (const float*)d_in[5];
  const float* e_l1g = (const float*)d_in[6];
  const float* e_l1b = (const float*)d_in[7];
  const float* e_l2g = (const float*)d_in[8];
  const float* e_l2b = (const float*)d_in[9];
  const float* e_f1w = (const float*)d_in[10];
  const float* e_f1b = (const float*)d_in[11];
  const float* e_f2w = (const float*)d_in[12];
  const float* e_f2b = (const float*)d_in[13];
  const float* e_ng  = (const float*)d_in[14];
  const float* e_nb  = (const float*)d_in[15];
  const float* d_saw = (const float*)d_in[16];
  const float* d_sab = (const float*)d_in[17];
  const float* d_saow= (const float*)d_in[18];
  const float* d_saob= (const float*)d_in[19];
  const float* d_caw = (const float*)d_in[20];
  const float* d_cab = (const float*)d_in[21];
  const float* d_caow= (const float*)d_in[22];
  const float* d_caob= (const float*)d_in[23];
  const float* d_l1g = (const float*)d_in[24];
  const float* d_l1b = (const float*)d_in[25];
  const float* d_l2g = (const float*)d_in[26];
  const float* d_l2b = (const float*)d_in[27];
  const float* d_l3g = (const float*)d_in[28];
  const float* d_l3b = (const float*)d_in[29];
  const float* d_f1w = (const float*)d_in[30];
  const float* d_f1b = (const float*)d_in[31];
  const float* d_f2w = (const float*)d_in[32];
  const float* d_f2b = (const float*)d_in[33];
  const float* d_ng  = (const float*)d_in[34];
  const float* d_nb  = (const float*)d_in[35];
  const float* voc_w = (const float*)d_in[36];
  const float* voc_b = (const float*)d_in[37];
  float* out = (float*)d_out;

  // workspace carve-up (floats)
  float* p = (float*)d_ws;
  auto alloc = [&](size_t n) { float* r = p; p += n; return r; };
  float* enc_x   = alloc(192 * 512);
  float* enc_tmp = alloc(192 * 2048);
  float* enc_ao  = alloc(192 * 512);
  float* enc_raw = alloc(192 * 512);
  float* mem_k   = alloc(3 * 192 * 512);
  float* mem_v   = alloc(3 * 192 * 512);
  float* partE   = alloc(4 * 192 * 512);   // encoder ffn2 partials
  float* dqkv    = alloc(8 * 1536);
  float* y_in    = alloc(8 * 512);
  float* y1      = alloc(8 * 512);
  float* y2      = alloc(8 * 512);
  float* qca     = alloc(8 * 512);
  float* dmid    = alloc(8 * 2048);
  float* partD   = alloc(4 * 8 * 512);     // decoder ffn2 partials
  float* partSA  = alloc(8 * 8 * 512);     // self-attn out-proj head partials
  float* partCA  = alloc(8 * 8 * 512);     // cross-attn out-proj head partials
  float* cacheK  = alloc(3 * LBUF * 8 * 512);
  float* cacheV  = alloc(3 * LBUF * 8 * 512);
  int* tokens    = (int*)alloc(LBUF * 8);
  unsigned long long* amax = (unsigned long long*)alloc(16);

// 12-null tail: amax, lng, lnb, lng2, lnb2, astore, gtok, gemb, rpart, rbias, rresid, rS
#define FGZ nullptr, nullptr, nullptr, nullptr, nullptr, nullptr, nullptr, nullptr, nullptr, nullptr, nullptr, 0

  // ---------------- encoder ----------------
  enc_embed_kernel<<<dim3(192), dim3(256), 0, stream>>>(inp, emb, enc_x);
  for (int l = 0; l < NL; ++l) {
    const float* w  = e_aw  + (size_t)l * E * 3 * E;
    const float* bq = e_ab  + (size_t)l * 3 * E;
    if (l == 0) {
      fgemm_kernel<<<dim3(24, 1, 24), dim3(256), 0, stream>>>(
          enc_x, E, w, 3 * E, 3 * E, bq, nullptr, enc_tmp, 0, FGZ);
    } else {
      fgemm_kernel<<<dim3(24, 1, 24), dim3(256), 0, stream>>>(
          enc_raw, E, w, 3 * E, 3 * E, bq, nullptr, enc_tmp, 0,
          nullptr, e_l2g + (size_t)(l - 1) * E, e_l2b + (size_t)(l - 1) * E,
          nullptr, nullptr, enc_x,
          nullptr, nullptr, nullptr, nullptr, nullptr, 0);
    }
    enc_attn_kernel<<<dim3(64), dim3(256), 0, stream>>>(enc_tmp, enc_ao);
    fgemm_kernel<<<dim3(8, 1, 24), dim3(256), 0, stream>>>(
        enc_ao, E, e_aow + (size_t)l * E * E, E, E, e_aob + (size_t)l * E,
        enc_x, enc_raw, 0, FGZ);
    fgemm_kernel<<<dim3(32, 1, 24), dim3(256), 0, stream>>>(
        enc_raw, E, e_f1w + (size_t)l * E * FF, FF, FF, e_f1b + (size_t)l * FF,
        nullptr, enc_tmp, 1,
        nullptr, e_l1g + (size_t)l * E, e_l1b + (size_t)l * E,
        nullptr, nullptr, enc_x,
        nullptr, nullptr, nullptr, nullptr, nullptr, 0);
    fgemm_kernel<<<dim3(8, 4, 24), dim3(256), 0, stream>>>(
        enc_tmp, FF, e_f2w + (size_t)l * FF * E, E, E, nullptr,
        nullptr, partE, 0, FGZ);
    reduce_br_kernel<<<dim3(192), dim3(256), 0, stream>>>(
        partE, 4, 192, e_f2b + (size_t)l * E, enc_x, enc_raw);
  }

  // cross-attn K,V for memory: double-LN (ln2[2] then final ng) fused in prologue
  for (int l = 0; l < NL; ++l) {
    const float* w  = d_caw + (size_t)l * E * 3 * E;
    const float* bq = d_cab + (size_t)l * 3 * E;
    fgemm_kernel<<<dim3(8, 1, 24), dim3(256), 0, stream>>>(
        enc_raw, E, w + E, 3 * E, E, bq + E, nullptr,
        mem_k + (size_t)l * 192 * 512, 0,
        nullptr, e_l2g + (size_t)2 * E, e_l2b + (size_t)2 * E,
        e_ng, e_nb, nullptr,
        nullptr, nullptr, nullptr, nullptr, nullptr, 0);
    fgemm_kernel<<<dim3(8, 1, 24), dim3(256), 0, stream>>>(
        enc_raw, E, w + 2 * E, 3 * E, E, bq + 2 * E, nullptr,
        mem_v + (size_t)l * 192 * 512, 0,
        nullptr, e_l2g + (size_t)2 * E, e_l2b + (size_t)2 * E,
        e_ng, e_nb, nullptr,
        nullptr, nullptr, nullptr, nullptr, nullptr, 0);
  }

  // ---------------- greedy decode (KV-cached, head-partial out-proj) -------
  dec_init_kernel<<<dim3(1), dim3(64), 0, stream>>>(tokens, amax);
  for (int i = 0; i < ML; ++i) {
    for (int l = 0; l < NL; ++l) {
      const float* saw = d_saw + (size_t)l * E * 3 * E;
      const float* sab = d_sab + (size_t)l * 3 * E;
      const float* caw = d_caw + (size_t)l * E * 3 * E;
      const float* cab = d_cab + (size_t)l * 3 * E;
      float* Kc = cacheK + (size_t)l * LBUF * 8 * 512;
      float* Vc = cacheV + (size_t)l * LBUF * 8 * 512;

      // QKV. l==0: fused embed gather (astore y_in).
      // l>0: fused FFN2-reduce of previous layer + LN3 (astore y_in).
      if (l == 0) {
        fgemm_kernel<<<dim3(24, 1, 1), dim3(256), 0, stream>>>(
            nullptr, E, saw, 3 * E, 3 * E, sab, nullptr, dqkv, 0,
            nullptr, nullptr, nullptr, nullptr, nullptr, y_in,
            tokens + (size_t)i * BB, emb,
            nullptr, nullptr, nullptr, 0);
      } else {
        fgemm_kernel<<<dim3(24, 1, 1), dim3(256), 0, stream>>>(
            nullptr, E, saw, 3 * E, 3 * E, sab, nullptr, dqkv, 0,
            nullptr, d_l3g + (size_t)(l - 1) * E, d_l3b + (size_t)(l - 1) * E,
            nullptr, nullptr, y_in,
            nullptr, nullptr,
            partD, d_f2b + (size_t)(l - 1) * E, y2, 4);
      }
      // self-attn + partial out-proj (64 blocks, no redundancy)
      dec_sa_part_kernel<<<dim3(64), dim3(256), 0, stream>>>(
          dqkv, Kc, Vc, i, d_saow + (size_t)l * E * E, partSA);
      // q-projection: prologue = head-partial reduce + bias + resid + LN1 (astore y1)
      fgemm_kernel<<<dim3(8, 1, 1), dim3(256), 0, stream>>>(
          nullptr, E, caw, 3 * E, E, cab, nullptr, qca, 0,
          nullptr, d_l1g + (size_t)l * E, d_l1b + (size_t)l * E,
          nullptr, nullptr, y1,
          nullptr, nullptr,
          partSA, d_saob + (size_t)l * E, y_in, 8);
      // cross-attn + partial out-proj
      dec_ca_part_kernel<<<dim3(64), dim3(256), 0, stream>>>(
          qca, mem_k + (size_t)l * 192 * 512, mem_v + (size_t)l * 192 * 512,
          d_caow + (size_t)l * E * E, partCA);
      // FFN1: prologue = head-partial reduce + bias + resid + LN2 (astore y2) + relu
      fgemm_kernel<<<dim3(32, 1, 1), dim3(256), 0, stream>>>(
          nullptr, E, d_f1w + (size_t)l * E * FF, FF, FF, d_f1b + (size_t)l * FF,
          nullptr, dmid, 1,
          nullptr, d_l2g + (size_t)l * E, d_l2b + (size_t)l * E,
          nullptr, nullptr, y2,
          nullptr, nullptr,
          partCA, d_caob + (size_t)l * E, y1, 8);
      // FFN2 partials (k-split)
      fgemm_kernel<<<dim3(8, 4, 1), dim3(256), 0, stream>>>(
          dmid, FF, d_f2w + (size_t)l * FF * E, E, E, nullptr,
          nullptr, partD, 0, FGZ);
    }
    // last layer's FFN2 reduce + LN3
    reduce_ln_kernel<<<dim3(8), dim3(256), 0, stream>>>(
        partD, 4, d_f2b + (size_t)(NL - 1) * E, y2,
        d_l3g + (size_t)(NL - 1) * E, d_l3b + (size_t)(NL - 1) * E, y_in);

    float* dist_i = out + 192 + (size_t)i * (8 * VTOK);
    // final decoder norm fused into vocab GEMM prologue + argmax keys
    fgemm_kernel<<<dim3(500, 1, 1), dim3(256), 0, stream>>>(
        y_in, E, voc_w, VTOK, VTOK, voc_b, nullptr, dist_i, 0,
        amax, d_ng, d_nb, nullptr, nullptr, nullptr,
        nullptr, nullptr, nullptr, nullptr, nullptr, 0);
    next_token_kernel<<<dim3(1), dim3(64), 0, stream>>>(amax, tokens, out, i);
  }
#undef FGZ
}

// Round 8
// 5968.568 us; speedup vs baseline: 1.2176x; 1.2176x over previous
//
#include <hip/hip_runtime.h>
#include <stdint.h>

#define E    512
#define H    8
#define DH   64
#define BB   8
#define SS   24
#define FF   2048
#define NL   3
#define VTOK 32000
#define LBUF 25
#define ML   24
#define START_ID 1

// ---------------------------------------------------------------------------
// Encoder embedding + sinusoidal PE (double to match numpy)
// ---------------------------------------------------------------------------
__global__ void enc_embed_kernel(const int* __restrict__ inp, const float* __restrict__ emb,
                                 float* __restrict__ x) {
  int r = blockIdx.x;
  int s = r / BB, b = r % BB;
  int tok = inp[b * SS + s];
  const float* er = emb + (size_t)tok * E;
  for (int e = threadIdx.x; e < E; e += blockDim.x) {
    int j = e >> 1;
    double dv = exp(-((double)(2 * j)) * (log(10000.0) / (double)E));
    double ang = (double)s * dv;
    double pe = (e & 1) ? cos(ang) : sin(ang);
    x[(size_t)r * E + e] = er[e] + (float)pe;
  }
}

// ---------------------------------------------------------------------------
// Row LayerNorm: grid = rows, block = 256
// ---------------------------------------------------------------------------
__global__ __launch_bounds__(256) void ln_kernel(const float* __restrict__ x,
                          const float* __restrict__ g,
                          const float* __restrict__ bta, float* __restrict__ y) {
  int r = blockIdx.x;
  int t = threadIdx.x;
  const float* xr = x + (size_t)r * E;
  float a0 = xr[t], a1 = xr[t + 256];
  __shared__ float red[256];
  red[t] = a0 + a1;
  __syncthreads();
  for (int s = 128; s > 0; s >>= 1) { if (t < s) red[t] += red[t + s]; __syncthreads(); }
  float m = red[0] * (1.0f / (float)E);
  __syncthreads();
  float d0 = a0 - m, d1 = a1 - m;
  red[t] = d0 * d0 + d1 * d1;
  __syncthreads();
  for (int s = 128; s > 0; s >>= 1) { if (t < s) red[t] += red[t + s]; __syncthreads(); }
  float v = red[0] * (1.0f / (float)E);
  float rstd = 1.0f / sqrtf(v + 1e-5f);
  y[(size_t)r * E + t]       = d0 * rstd * g[t]       + bta[t];
  y[(size_t)r * E + t + 256] = d1 * rstd * g[t + 256] + bta[t + 256];
}

// ---------------------------------------------------------------------------
// Fast GEMM: C[M,N] = A[M,K] @ W[K,N(ldw)] (+bias,resid,relu / or partials)
// grid (N/64, S, M/8), block 256. Block: 64 cols, 512-k slice, 8 rows.
// Thread t: tc=t&15 -> cols c0+tc*4 (float4 loads), tk=t>>4 -> k = tk+16i.
// 16-way k-split in block reduced through LDS. S>1 -> write partials [S][M][N].
// Per thread ~8 outstanding float4 loads (unroll 8) -> ~32KB in flight/block.
// ---------------------------------------------------------------------------
__global__ __launch_bounds__(256) void fgemm_kernel(
    const float* __restrict__ A, int K,
    const float* __restrict__ W, int ldw, int N,
    const float* __restrict__ bias,
    const float* __restrict__ resid,
    float* __restrict__ C, int relu,
    unsigned long long* __restrict__ amax) {
  __shared__ float Al[8 * 512];      // 16 KB
  __shared__ float red[16 * 512];    // 32 KB
  int t = threadIdx.x;
  int c0 = blockIdx.x * 64;
  int s = blockIdx.y;
  int row0 = blockIdx.z * 8;
  int kbase = s * 512;
  // A tile: 8 rows x 512 k
  for (int i = t; i < 1024; i += 256) {
    int r = i >> 7, cc = i & 127;
    ((float4*)Al)[i] = *(const float4*)(A + (size_t)(row0 + r) * K + kbase + (cc << 2));
  }
  __syncthreads();
  int tc = t & 15, tk = t >> 4;
  int col = c0 + (tc << 2);
  float acc[8][4];
#pragma unroll
  for (int m = 0; m < 8; ++m) { acc[m][0] = acc[m][1] = acc[m][2] = acc[m][3] = 0.f; }
  const float4* wp = (const float4*)(W + (size_t)kbase * ldw + col);
  const size_t ld4 = (size_t)(ldw >> 2);
#pragma unroll 8
  for (int i = 0; i < 32; ++i) {
    int k = tk + (i << 4);
    float4 wv = wp[(size_t)k * ld4];
#pragma unroll
    for (int m = 0; m < 8; ++m) {
      float a = Al[m * 512 + k];
      acc[m][0] += a * wv.x; acc[m][1] += a * wv.y;
      acc[m][2] += a * wv.z; acc[m][3] += a * wv.w;
    }
  }
  // dump per-tk partials to LDS: red[tk][m*64 + tc*4 ..]
#pragma unroll
  for (int m = 0; m < 8; ++m) {
    float4* rr = (float4*)&red[tk * 512 + m * 64 + (tc << 2)];
    *rr = make_float4(acc[m][0], acc[m][1], acc[m][2], acc[m][3]);
  }
  __syncthreads();
  float out2[2];
#pragma unroll
  for (int j = 0; j < 2; ++j) {
    int o = t + j * 256;
    float v = 0.f;
#pragma unroll
    for (int sl = 0; sl < 16; ++sl) v += red[sl * 512 + o];
    out2[j] = v;
  }
  int S = gridDim.y;
  if (S > 1) {
    // partials: [s][row][col], M = gridDim.z*8
    int M = gridDim.z * 8;
#pragma unroll
    for (int j = 0; j < 2; ++j) {
      int o = t + j * 256; int m = o >> 6, cc = o & 63;
      C[((size_t)s * M + row0 + m) * N + c0 + cc] = out2[j];
    }
  } else {
#pragma unroll
    for (int j = 0; j < 2; ++j) {
      int o = t + j * 256; int m = o >> 6, cc = o & 63;
      int col2 = c0 + cc;
      float v = out2[j] + bias[col2];
      if (resid) v += resid[(size_t)(row0 + m) * N + col2];
      if (relu) v = fmaxf(v, 0.0f);
      C[(size_t)(row0 + m) * N + col2] = v;
      out2[j] = v;
    }
    if (amax) {
      __syncthreads();
      unsigned long long* keys = (unsigned long long*)red;
#pragma unroll
      for (int j = 0; j < 2; ++j) {
        int o = t + j * 256;
        unsigned int fb = __float_as_uint(out2[j]);
        fb = (fb & 0x80000000u) ? ~fb : (fb | 0x80000000u);
        int col2 = c0 + (o & 63);
        keys[o] = ((unsigned long long)fb << 32) |
                  (unsigned long long)(0xFFFFFFFFu - (unsigned)col2);
      }
      __syncthreads();
      if (t < 64) {
        for (int m = 0; m < 8; ++m) {
          unsigned long long k = keys[m * 64 + t];
          for (int off = 32; off; off >>= 1) {
            unsigned long long o2 = __shfl_down(k, off);
            if (o2 > k) k = o2;
          }
          if (t == 0) atomicMax(&amax[m], k);
        }
      }
    }
  }
}

// ---------------------------------------------------------------------------
// Reduce S partial slices + bias + resid (encoder FFN2). grid = M rows.
// ---------------------------------------------------------------------------
__global__ __launch_bounds__(256) void reduce_br_kernel(const float* __restrict__ part, int S, int M,
                                 const float* __restrict__ bias,
                                 const float* __restrict__ resid,
                                 float* __restrict__ outp) {
  int r = blockIdx.x, t = threadIdx.x;
#pragma unroll
  for (int j = 0; j < 2; ++j) {
    int c = t + j * 256;
    float v = bias[c] + resid[(size_t)r * E + c];
    for (int s = 0; s < S; ++s) v += part[((size_t)s * M + r) * E + c];
    outp[(size_t)r * E + c] = v;
  }
}

// ---------------------------------------------------------------------------
// Reduce S partial slices + bias + resid + LayerNorm (decoder FFN2). grid 8.
// ---------------------------------------------------------------------------
__global__ __launch_bounds__(256) void reduce_ln_kernel(const float* __restrict__ part, int S,
                                 const float* __restrict__ bias,
                                 const float* __restrict__ resid,
                                 const float* __restrict__ g, const float* __restrict__ bta,
                                 float* __restrict__ out) {
  int b = blockIdx.x, t = threadIdx.x;
  float v0 = bias[t] + resid[(size_t)b * E + t];
  float v1 = bias[t + 256] + resid[(size_t)b * E + t + 256];
  for (int s = 0; s < S; ++s) {
    v0 += part[((size_t)s * 8 + b) * E + t];
    v1 += part[((size_t)s * 8 + b) * E + t + 256];
  }
  __shared__ float red[256];
  red[t] = v0 + v1;
  __syncthreads();
  for (int s = 128; s > 0; s >>= 1) { if (t < s) red[t] += red[t + s]; __syncthreads(); }
  float m = red[0] * (1.0f / (float)E);
  __syncthreads();
  float d0 = v0 - m, d1 = v1 - m;
  red[t] = d0 * d0 + d1 * d1;
  __syncthreads();
  for (int s = 128; s > 0; s >>= 1) { if (t < s) red[t] += red[t + s]; __syncthreads(); }
  float v = red[0] * (1.0f / (float)E);
  float rstd = 1.0f / sqrtf(v + 1e-5f);
  out[(size_t)b * E + t]       = d0 * rstd * g[t]       + bta[t];
  out[(size_t)b * E + t + 256] = d1 * rstd * g[t + 256] + bta[t + 256];
}

// ---------------------------------------------------------------------------
// Encoder self-attention: block per (b,h), 256 threads.
// ---------------------------------------------------------------------------
__global__ void enc_attn_kernel(const float* __restrict__ qkv, float* __restrict__ o) {
  int b = blockIdx.x >> 3, h = blockIdx.x & 7;
  __shared__ float qs[SS * DH], ks[SS * DH], vs[SS * DH];
  __shared__ float sc[SS][SS];
  int t = threadIdx.x;
  for (int idx = t; idx < SS * DH; idx += 256) {
    int srow = idx / DH, d = idx - srow * DH;
    size_t base = ((size_t)(srow * BB + b)) * (3 * E) + h * DH + d;
    qs[idx] = qkv[base];
    ks[idx] = qkv[base + E];
    vs[idx] = qkv[base + 2 * E];
  }
  __syncthreads();
  for (int p = t; p < SS * SS; p += 256) {
    int qi = p / SS, kj = p - qi * SS;
    float a = 0.f;
    for (int d = 0; d < DH; ++d) a += qs[qi * DH + d] * ks[kj * DH + d];
    sc[qi][kj] = a * 0.125f;
  }
  __syncthreads();
  if (t < SS) {
    float mx = -1e30f;
    for (int j = 0; j < SS; ++j) mx = fmaxf(mx, sc[t][j]);
    float sm = 0.f;
    for (int j = 0; j < SS; ++j) { float ev = expf(sc[t][j] - mx); sc[t][j] = ev; sm += ev; }
    float inv = 1.0f / sm;
    for (int j = 0; j < SS; ++j) sc[t][j] *= inv;
  }
  __syncthreads();
  for (int p = t; p < SS * DH; p += 256) {
    int qi = p / DH, d = p - qi * DH;
    float a = 0.f;
    for (int j = 0; j < SS; ++j) a += sc[qi][j] * vs[j * DH + d];
    o[((size_t)(qi * BB + b)) * E + h * DH + d] = a;
  }
}

// ---------------------------------------------------------------------------
// Decoder self-attn (standalone): grid 64=(b,h), 64 threads.
// qkv row layout [b][3E]. Updates KV cache at pos, attends 0..pos.
// ---------------------------------------------------------------------------
__global__ __launch_bounds__(64) void dec_sa_attn_kernel(const float* __restrict__ qkv,
                                   float* __restrict__ Kc, float* __restrict__ Vc,
                                   float* __restrict__ o, int pos) {
  int b = blockIdx.x >> 3, h = blockIdx.x & 7;
  int t = threadIdx.x;
  const float* qp = qkv + (size_t)b * (3 * E) + h * DH;
  const float* kn = qp + E;
  const float* vn = qp + 2 * E;
  float* kc = Kc + ((size_t)pos * BB + b) * E + h * DH;
  float* vc = Vc + ((size_t)pos * BB + b) * E + h * DH;
  __shared__ float qs[DH];
  __shared__ float sc[32];
  kc[t] = kn[t]; vc[t] = vn[t]; qs[t] = qp[t];
  __syncthreads();
  int L = pos + 1;
  if (t < L) {
    const float* kr = (t == pos) ? kn : (Kc + ((size_t)t * BB + b) * E + h * DH);
    float a = 0.f;
#pragma unroll 8
    for (int d = 0; d < DH; ++d) a += qs[d] * kr[d];
    sc[t] = a * 0.125f;
  }
  __syncthreads();
  if (t == 0) {
    float mx = -1e30f;
    for (int j = 0; j < L; ++j) mx = fmaxf(mx, sc[j]);
    float sm = 0.f;
    for (int j = 0; j < L; ++j) { float ev = expf(sc[j] - mx); sc[j] = ev; sm += ev; }
    float inv = 1.0f / sm;
    for (int j = 0; j < L; ++j) sc[j] *= inv;
  }
  __syncthreads();
  float a = 0.f;
  for (int j = 0; j < L; ++j) {
    const float* vr = (j == pos) ? vn : (Vc + ((size_t)j * BB + b) * E + h * DH);
    a += sc[j] * vr[t];
  }
  o[(size_t)b * E + h * DH + t] = a;
}

// ---------------------------------------------------------------------------
// Decoder cross-attn (standalone): grid 64=(b,h), 64 threads.
// ---------------------------------------------------------------------------
__global__ __launch_bounds__(64) void dec_ca_attn_kernel(const float* __restrict__ q,
                                   const float* __restrict__ Km, const float* __restrict__ Vm,
                                   float* __restrict__ o) {
  int b = blockIdx.x >> 3, h = blockIdx.x & 7;
  int t = threadIdx.x;
  __shared__ float qs[DH];
  __shared__ float sc[SS];
  qs[t] = q[(size_t)b * E + h * DH + t];
  __syncthreads();
  if (t < SS) {
    const float* kr = Km + ((size_t)t * BB + b) * E + h * DH;
    float a = 0.f;
#pragma unroll 8
    for (int d = 0; d < DH; ++d) a += qs[d] * kr[d];
    sc[t] = a * 0.125f;
  }
  __syncthreads();
  if (t == 0) {
    float mx = -1e30f;
    for (int j = 0; j < SS; ++j) mx = fmaxf(mx, sc[j]);
    float sm = 0.f;
    for (int j = 0; j < SS; ++j) { float ev = expf(sc[j] - mx); sc[j] = ev; sm += ev; }
    float inv = 1.0f / sm;
    for (int j = 0; j < SS; ++j) sc[j] *= inv;
  }
  __syncthreads();
  float a = 0.f;
  for (int j = 0; j < SS; ++j) a += sc[j] * Vm[((size_t)j * BB + b) * E + h * DH + t];
  o[(size_t)b * E + h * DH + t] = a;
}

// ---------------------------------------------------------------------------
__global__ void dec_embed_kernel(const int* __restrict__ tokens, const float* __restrict__ emb,
                                 float* __restrict__ y, int i) {
  int b = blockIdx.x;
  int tok = tokens[i * BB + b];
  const float* er = emb + (size_t)tok * E;
  for (int e = threadIdx.x; e < E; e += blockDim.x) y[(size_t)b * E + e] = er[e];
}

__global__ void dec_init_kernel(int* __restrict__ tokens, unsigned long long* __restrict__ amax) {
  int t = threadIdx.x;
  if (t < BB) { tokens[t] = START_ID; amax[t] = 0ull; }
}

__global__ void next_token_kernel(unsigned long long* __restrict__ amax, int* __restrict__ tokens,
                                  float* __restrict__ outtok, int i) {
  int t = threadIdx.x;
  if (t < BB) {
    unsigned long long p = amax[t];
    int idx = (int)(0xFFFFFFFFu - (unsigned int)(p & 0xFFFFFFFFull));
    tokens[(i + 1) * BB + t] = idx;
    outtok[i * BB + t] = (float)idx;
    amax[t] = 0ull;
  }
}

// ---------------------------------------------------------------------------
extern "C" void kernel_launch(void* const* d_in, const int* in_sizes, int n_in,
                              void* d_out, int out_size, void* d_ws, size_t ws_size,
                              hipStream_t stream) {
  (void)in_sizes; (void)n_in; (void)out_size; (void)ws_size;
  const int*   inp   = (const int*)d_in[0];
  const float* emb   = (const float*)d_in[1];
  const float* e_aw  = (const float*)d_in[2];
  const float* e_ab  = (const float*)d_in[3];
  const float* e_aow = (const float*)d_in[4];
  const float* e_aob = (const float*)d_in[5];
  const float* e_l1g = (const float*)d_in[6];
  const float* e_l1b = (const float*)d_in[7];
  const float* e_l2g = (const float*)d_in[8];
  const float* e_l2b = (const float*)d_in[9];
  const float* e_f1w = (const float*)d_in[10];
  const float* e_f1b = (const float*)d_in[11];
  const float* e_f2w = (const float*)d_in[12];
  const float* e_f2b = (const float*)d_in[13];
  const float* e_ng  = (const float*)d_in[14];
  const float* e_nb  = (const float*)d_in[15];
  const float* d_saw = (const float*)d_in[16];
  const float* d_sab = (const float*)d_in[17];
  const float* d_saow= (const float*)d_in[18];
  const float* d_saob= (const float*)d_in[19];
  const float* d_caw = (const float*)d_in[20];
  const float* d_cab = (const float*)d_in[21];
  const float* d_caow= (const float*)d_in[22];
  const float* d_caob= (const float*)d_in[23];
  const float* d_l1g = (const float*)d_in[24];
  const float* d_l1b = (const float*)d_in[25];
  const float* d_l2g = (const float*)d_in[26];
  const float* d_l2b = (const float*)d_in[27];
  const float* d_l3g = (const float*)d_in[28];
  const float* d_l3b = (const float*)d_in[29];
  const float* d_f1w = (const float*)d_in[30];
  const float* d_f1b = (const float*)d_in[31];
  const float* d_f2w = (const float*)d_in[32];
  const float* d_f2b = (const float*)d_in[33];
  const float* d_ng  = (const float*)d_in[34];
  const float* d_nb  = (const float*)d_in[35];
  const float* voc_w = (const float*)d_in[36];
  const float* voc_b = (const float*)d_in[37];
  float* out = (float*)d_out;

  // workspace carve-up (floats)
  float* p = (float*)d_ws;
  auto alloc = [&](size_t n) { float* r = p; p += n; return r; };
  float* enc_x   = alloc(192 * 512);
  float* enc_tmp = alloc(192 * 2048);
  float* enc_ao  = alloc(192 * 512);
  float* enc_raw = alloc(192 * 512);
  float* memry   = alloc(192 * 512);
  float* mem_k   = alloc(3 * 192 * 512);
  float* mem_v   = alloc(3 * 192 * 512);
  float* partE   = alloc(4 * 192 * 512);   // encoder ffn2 partials
  float* dqkv    = alloc(8 * 1536);
  float* y_in    = alloc(8 * 512);
  float* o_sa    = alloc(8 * 512);
  float* y1      = alloc(8 * 512);
  float* y1raw   = alloc(8 * 512);
  float* qca     = alloc(8 * 512);
  float* oca     = alloc(8 * 512);
  float* y2      = alloc(8 * 512);
  float* y2raw   = alloc(8 * 512);
  float* yf      = alloc(8 * 512);
  float* dmid    = alloc(8 * 2048);
  float* partD   = alloc(4 * 8 * 512);     // decoder ffn2 partials
  float* cacheK  = alloc(3 * LBUF * 8 * 512);
  float* cacheV  = alloc(3 * LBUF * 8 * 512);
  int* tokens    = (int*)alloc(LBUF * 8);
  unsigned long long* amax = (unsigned long long*)alloc(16);

  // ---------------- encoder ----------------
  enc_embed_kernel<<<dim3(192), dim3(256), 0, stream>>>(inp, emb, enc_x);
  for (int l = 0; l < NL; ++l) {
    const float* w  = e_aw  + (size_t)l * E * 3 * E;
    const float* bq = e_ab  + (size_t)l * 3 * E;
    fgemm_kernel<<<dim3(24, 1, 24), dim3(256), 0, stream>>>(
        enc_x, E, w, 3 * E, 3 * E, bq, nullptr, enc_tmp, 0, nullptr);
    enc_attn_kernel<<<dim3(64), dim3(256), 0, stream>>>(enc_tmp, enc_ao);
    fgemm_kernel<<<dim3(8, 1, 24), dim3(256), 0, stream>>>(
        enc_ao, E, e_aow + (size_t)l * E * E, E, E, e_aob + (size_t)l * E,
        enc_x, enc_raw, 0, nullptr);
    ln_kernel<<<dim3(192), dim3(256), 0, stream>>>(enc_raw, e_l1g + l * E, e_l1b + l * E, enc_x);
    fgemm_kernel<<<dim3(32, 1, 24), dim3(256), 0, stream>>>(
        enc_x, E, e_f1w + (size_t)l * E * FF, FF, FF, e_f1b + (size_t)l * FF,
        nullptr, enc_tmp, 1, nullptr);
    fgemm_kernel<<<dim3(8, 4, 24), dim3(256), 0, stream>>>(
        enc_tmp, FF, e_f2w + (size_t)l * FF * E, E, E, nullptr,
        nullptr, partE, 0, nullptr);
    reduce_br_kernel<<<dim3(192), dim3(256), 0, stream>>>(
        partE, 4, 192, e_f2b + (size_t)l * E, enc_x, enc_raw);
    ln_kernel<<<dim3(192), dim3(256), 0, stream>>>(enc_raw, e_l2g + l * E, e_l2b + l * E, enc_x);
  }
  ln_kernel<<<dim3(192), dim3(256), 0, stream>>>(enc_x, e_ng, e_nb, memry);

  // cross-attn K,V for memory (fixed across decode steps)
  for (int l = 0; l < NL; ++l) {
    const float* w  = d_caw + (size_t)l * E * 3 * E;
    const float* bq = d_cab + (size_t)l * 3 * E;
    fgemm_kernel<<<dim3(8, 1, 24), dim3(256), 0, stream>>>(
        memry, E, w + E, 3 * E, E, bq + E, nullptr,
        mem_k + (size_t)l * 192 * 512, 0, nullptr);
    fgemm_kernel<<<dim3(8, 1, 24), dim3(256), 0, stream>>>(
        memry, E, w + 2 * E, 3 * E, E, bq + 2 * E, nullptr,
        mem_v + (size_t)l * 192 * 512, 0, nullptr);
  }

  // ---------------- greedy decode (KV-cached incremental) ----------------
  dec_init_kernel<<<dim3(1), dim3(64), 0, stream>>>(tokens, amax);
  for (int i = 0; i < ML; ++i) {
    dec_embed_kernel<<<dim3(8), dim3(256), 0, stream>>>(tokens, emb, y_in, i);
    for (int l = 0; l < NL; ++l) {
      const float* saw = d_saw + (size_t)l * E * 3 * E;
      const float* sab = d_sab + (size_t)l * 3 * E;
      const float* caw = d_caw + (size_t)l * E * 3 * E;
      const float* cab = d_cab + (size_t)l * 3 * E;
      float* Kc = cacheK + (size_t)l * LBUF * 8 * 512;
      float* Vc = cacheV + (size_t)l * LBUF * 8 * 512;

      fgemm_kernel<<<dim3(24, 1, 1), dim3(256), 0, stream>>>(
          y_in, E, saw, 3 * E, 3 * E, sab, nullptr, dqkv, 0, nullptr);
      dec_sa_attn_kernel<<<dim3(64), dim3(64), 0, stream>>>(dqkv, Kc, Vc, o_sa, i);
      fgemm_kernel<<<dim3(8, 1, 1), dim3(256), 0, stream>>>(
          o_sa, E, d_saow + (size_t)l * E * E, E, E, d_saob + (size_t)l * E,
          y_in, y1raw, 0, nullptr);
      ln_kernel<<<dim3(8), dim3(256), 0, stream>>>(y1raw, d_l1g + l * E, d_l1b + l * E, y1);

      fgemm_kernel<<<dim3(8, 1, 1), dim3(256), 0, stream>>>(
          y1, E, caw, 3 * E, E, cab, nullptr, qca, 0, nullptr);
      dec_ca_attn_kernel<<<dim3(64), dim3(64), 0, stream>>>(
          qca, mem_k + (size_t)l * 192 * 512, mem_v + (size_t)l * 192 * 512, oca);
      fgemm_kernel<<<dim3(8, 1, 1), dim3(256), 0, stream>>>(
          oca, E, d_caow + (size_t)l * E * E, E, E, d_caob + (size_t)l * E,
          y1, y2raw, 0, nullptr);
      ln_kernel<<<dim3(8), dim3(256), 0, stream>>>(y2raw, d_l2g + l * E, d_l2b + l * E, y2);

      fgemm_kernel<<<dim3(32, 1, 1), dim3(256), 0, stream>>>(
          y2, E, d_f1w + (size_t)l * E * FF, FF, FF, d_f1b + (size_t)l * FF,
          nullptr, dmid, 1, nullptr);
      fgemm_kernel<<<dim3(8, 4, 1), dim3(256), 0, stream>>>(
          dmid, FF, d_f2w + (size_t)l * FF * E, E, E, nullptr,
          nullptr, partD, 0, nullptr);
      reduce_ln_kernel<<<dim3(8), dim3(256), 0, stream>>>(
          partD, 4, d_f2b + (size_t)l * E, y2, d_l3g + l * E, d_l3b + l * E, y_in);
    }
    ln_kernel<<<dim3(8), dim3(256), 0, stream>>>(y_in, d_ng, d_nb, yf);

    float* dist_i = out + 192 + (size_t)i * (8 * VTOK);
    fgemm_kernel<<<dim3(500, 1, 1), dim3(256), 0, stream>>>(
        yf, E, voc_w, VTOK, VTOK, voc_b, nullptr, dist_i, 0, amax);
    next_token_kernel<<<dim3(1), dim3(64), 0, stream>>>(amax, tokens, out, i);
  }
}